// Round 8
// baseline (4782.808 us; speedup 1.0000x reference)
//
#include <hip/hip_runtime.h>
#include <hip/hip_bf16.h>
#include <cstdint>
#include <cstddef>

#define NTOK 2048
#define HID  2048
#define NINT 5632
#define NEXP 8

typedef __attribute__((ext_vector_type(8))) short short8;
typedef __attribute__((ext_vector_type(4))) float f32x4;
typedef __attribute__((ext_vector_type(4))) float fl4;

__device__ __forceinline__ unsigned short f2bf(float f) {
    union { float f; unsigned int u; } v; v.f = f;
    unsigned int r = (v.u + 0x7fffu + ((v.u >> 16) & 1u)) >> 16;
    return (unsigned short)r;
}

// pack 2 floats -> 2 bf16 (v_cvt_pk_bf16_f32, RNE)
__device__ __forceinline__ unsigned int pk2(float x, float y) {
    __hip_bfloat162 h = __float22bfloat162_rn(make_float2(x, y));
    union { __hip_bfloat162 h; unsigned int u; } c; c.h = h;
    return c.u;
}

// async global->LDS DMA, 16 B per lane: lane l reads gsrc(l) -> ldsbase + l*16
__device__ __forceinline__ void gload16(const void* g, void* l) {
    __builtin_amdgcn_global_load_lds(
        (const __attribute__((address_space(1))) unsigned int*)g,
        (__attribute__((address_space(3))) unsigned int*)l, 16, 0, 0);
}

#define WAITV5() asm volatile("s_waitcnt vmcnt(5)" ::: "memory")
#define WAITV0() asm volatile("s_waitcnt vmcnt(0)" ::: "memory")
#define BAR()    __builtin_amdgcn_s_barrier()
#define SCH()    __builtin_amdgcn_sched_barrier(0)

// meta layout (ints): [0..7]=cnt, [8..15]=cursor, [16..24]=offs
__global__ void zero_kernel(float* __restrict__ out, int* __restrict__ meta) {
    int idx = blockIdx.x * blockDim.x + threadIdx.x;
    fl4 z = {0.f, 0.f, 0.f, 0.f};
    ((fl4*)out)[idx] = z;
    if (blockIdx.x == 0 && threadIdx.x < 16) meta[threadIdx.x] = 0;
}

__device__ __forceinline__ void top2_route(const float* __restrict__ lg, int t,
                                           int& e0, int& e1, float& w0, float& w1) {
    float l[NEXP];
#pragma unroll
    for (int e = 0; e < NEXP; ++e) l[e] = lg[t * NEXP + e];
    e0 = 0; float b0l = l[0];
#pragma unroll
    for (int e = 1; e < NEXP; ++e) if (l[e] > b0l) { b0l = l[e]; e0 = e; }
    e1 = (e0 == 0) ? 1 : 0; float b1l = l[e1];
#pragma unroll
    for (int e = 0; e < NEXP; ++e) {
        if (e == e0) continue;
        if (l[e] > b1l) { b1l = l[e]; e1 = e; }
    }
    float m = b0l;
    float p0 = __expf(b0l - m), p1 = __expf(b1l - m);
    float inv = 1.f / (p0 + p1);
    w0 = p0 * inv; w1 = p1 * inv;
}

__global__ void route_count(const float* __restrict__ logits, int* __restrict__ meta) {
    int t = blockIdx.x * blockDim.x + threadIdx.x;
    int e0, e1; float w0, w1;
    top2_route(logits, t, e0, e1, w0, w1);
    atomicAdd(&meta[e0], 1);
    atomicAdd(&meta[e1], 1);
}

__global__ void scan_kernel(int* __restrict__ meta) {
    if (threadIdx.x == 0 && blockIdx.x == 0) {
        int s = 0;
#pragma unroll
        for (int e = 0; e < NEXP; ++e) { meta[16 + e] = s; s += meta[e]; }
        meta[16 + NEXP] = s;
    }
}

__global__ void route_assign(const float* __restrict__ logits, int* __restrict__ meta,
                             int* __restrict__ rowTok, float* __restrict__ rowW) {
    int t = blockIdx.x * blockDim.x + threadIdx.x;
    int e0, e1; float w0, w1;
    top2_route(logits, t, e0, e1, w0, w1);
    int p0 = atomicAdd(&meta[8 + e0], 1);
    int s0 = meta[16 + e0] + p0;
    rowTok[s0] = t; rowW[s0] = w0;
    int p1 = atomicAdd(&meta[8 + e1], 1);
    int s1 = meta[16 + e1] + p1;
    rowTok[s1] = t; rowW[s1] = w1;
}

__global__ void gather_x(const float* __restrict__ x, const int* __restrict__ rowTok,
                         unsigned short* __restrict__ xg) {
    int slot = blockIdx.x;
    int tok = rowTok[slot];
    int c = threadIdx.x;
    const fl4* src = (const fl4*)(x + (size_t)tok * HID);
    fl4 a = src[c * 2], b = src[c * 2 + 1];
    short8 v;
    v[0] = (short)f2bf(a[0]); v[1] = (short)f2bf(a[1]); v[2] = (short)f2bf(a[2]); v[3] = (short)f2bf(a[3]);
    v[4] = (short)f2bf(b[0]); v[5] = (short)f2bf(b[1]); v[6] = (short)f2bf(b[2]); v[7] = (short)f2bf(b[3]);
    *(short8*)(xg + (size_t)slot * HID + c * 8) = v;
}

// ======================= GEMM CORE =======================
// Block: 1024 thr (16 waves = 4 row-groups x 4 col-groups). Tile: 256 A-rows.
// BK=32. A (bf16): global_load_lds into a TRIPLE-buffered ring (16 KB each),
// XOR-swizzled source so ds_read_b128 is conflict-free; A(k+2) issued at end
// of step k -> ~2 steps in flight. B (fp32 weights): per-wave cols, 2 named
// register sets, B(k+2) issued at end of step k -> 2 steps in flight.
// Steady state: one raw s_barrier + one counted vmcnt(5) per step
// (outstanding at step top = A(k),B(k),A(k+1),B(k+1) = 10 -> wait to 5).

#define GEMM_PRE(APTR, LDK)                                                      \
    const int tid = threadIdx.x;                                                 \
    const int wv = tid >> 6, l = tid & 63;                                       \
    const int cl = l & 15, kq = l >> 4;                                          \
    const int wr = wv >> 2, wc = wv & 3;                                         \
    int arow_ = cb + wv * 16 + (l >> 2);                                         \
    if (arow_ > Ne - 1) arow_ = Ne - 1;                                          \
    const unsigned short* gA = (APTR) + (size_t)(r0 + arow_) * (LDK)             \
                               + (((l & 3) ^ ((l >> 3) & 3)) << 3);              \
    char* a0 = (char*)As;                                                        \
    char* a1 = (char*)As + 16384;                                                \
    char* a2 = (char*)As + 32768;                                                \
    const int swzo = (kq ^ ((cl >> 1) & 3)) << 4;                                \
    const int aRowB = wr * 4096 + cl * 64 + swzo;                                \
    f32x4 acc[4][2];                                                             \
    _Pragma("unroll") for (int rf = 0; rf < 4; ++rf) {                           \
        acc[rf][0] = (f32x4){0.f, 0.f, 0.f, 0.f};                                \
        acc[rf][1] = (f32x4){0.f, 0.f, 0.f, 0.f};                                \
    }                                                                            \
    fl4 sA[4], sB[4];                                                            \
    short8 fg, fu;

#define LOADB(S) do {                                                            \
        S[0] = *(const fl4*)(p0g);                                               \
        S[1] = *(const fl4*)(p0g + 4);                                           \
        S[2] = *(const fl4*)(p1g);                                               \
        S[3] = *(const fl4*)(p1g + 4);                                           \
        p0g += 32; p1g += 32;                                                    \
    } while (0)

#define CVTB(S) do {                                                             \
        union { short8 s; unsigned int u[4]; } c0_, c1_;                         \
        c0_.u[0] = pk2(S[0][0], S[0][1]); c0_.u[1] = pk2(S[0][2], S[0][3]);      \
        c0_.u[2] = pk2(S[1][0], S[1][1]); c0_.u[3] = pk2(S[1][2], S[1][3]);      \
        c1_.u[0] = pk2(S[2][0], S[2][1]); c1_.u[1] = pk2(S[2][2], S[2][3]);      \
        c1_.u[2] = pk2(S[3][0], S[3][1]); c1_.u[3] = pk2(S[3][2], S[3][3]);      \
        fg = c0_.s; fu = c1_.s;                                                  \
    } while (0)

#define COMPUTE() do {                                                           \
        _Pragma("unroll") for (int rf = 0; rf < 4; ++rf) {                       \
            const short8 af_ = *(const short8*)(a0 + aRowB + rf * 1024);         \
            acc[rf][0] = __builtin_amdgcn_mfma_f32_16x16x32_bf16(af_, fg, acc[rf][0], 0, 0, 0); \
            acc[rf][1] = __builtin_amdgcn_mfma_f32_16x16x32_bf16(af_, fu, acc[rf][1], 0, 0, 0); \
        }                                                                        \
    } while (0)

#define STEP(K, S, NS) do {                                                      \
        if ((K) + 1 < (NS)) { WAITV5(); } else { WAITV0(); }                     \
        SCH();                                                                   \
        CVTB(S);                                                                 \
        BAR(); SCH();                                                            \
        COMPUTE();                                                               \
        SCH();                                                                   \
        if ((K) + 2 < (NS)) {                                                    \
            gload16(gA, a2 + wv * 1024); gA += 32;                               \
            LOADB(S);                                                            \
        }                                                                        \
        SCH();                                                                   \
        { char* t_ = a0; a0 = a1; a1 = a2; a2 = t_; }                            \
    } while (0)

#define PIPE(NS) do {                                                            \
        gload16(gA, a0 + wv * 1024); gA += 32;                                   \
        LOADB(sA);                                                               \
        gload16(gA, a1 + wv * 1024); gA += 32;                                   \
        LOADB(sB);                                                               \
        SCH();                                                                   \
        _Pragma("unroll 1")                                                      \
        for (int k = 0; k < (NS); k += 2) {                                      \
            STEP(k, sA, (NS));                                                   \
            STEP(k + 1, sB, (NS));                                               \
        }                                                                        \
    } while (0)

// ---------------- GEMM1: act = silu(xg@w1^T) * (xg@w3^T) ----------------
// Tile: 256 rows x 64 inter-cols (gate+up fused: wave owns 16 cols of both).
__global__ __launch_bounds__(1024) void gemm1_kernel(
        const unsigned short* __restrict__ xg,
        const float* __restrict__ w1, const float* __restrict__ w3,
        const int* __restrict__ meta, unsigned short* __restrict__ act) {
    const int ch = blockIdx.x;      // 8 chunks of 256 rows (x-fastest: adjacency)
    const int it = blockIdx.y;      // 88 tiles of 64 inter cols
    const int e  = blockIdx.z;      // 8 experts
    const int r0 = meta[16 + e];
    const int Ne = meta[17 + e] - r0;
    const int cb = ch * 256;
    if (cb >= Ne) return;

    __shared__ __align__(16) char As[3 * 16384];   // 48 KB ring

    GEMM_PRE(xg, HID)

    const int colg = it * 64 + wc * 16 + cl;
    const float* p0g = w1 + ((size_t)e * NINT + colg) * HID + kq * 8;
    const float* p1g = w3 + ((size_t)e * NINT + colg) * HID + kq * 8;

    PIPE(64);   // HID/32

    // epilogue: y = silu(gate)*up -> act bf16 (C: col=cl, row=kq*4+j)
#pragma unroll
    for (int rf = 0; rf < 4; ++rf) {
#pragma unroll
        for (int j = 0; j < 4; ++j) {
            int r = cb + wr * 64 + rf * 16 + kq * 4 + j;
            if (r < Ne) {
                float gv = acc[rf][0][j];
                float y = gv / (1.f + __expf(-gv)) * acc[rf][1][j];
                act[(size_t)(r0 + r) * NINT + it * 64 + wc * 16 + cl] = f2bf(y);
            }
        }
    }
}

// ---------------- GEMM2: out += rowW * (act @ w2^T) ----------------
// Tile: 256 rows x 128 hid-cols (wave owns 32 cols = 2 col-frags).
__global__ __launch_bounds__(1024) void gemm2_kernel(
        const unsigned short* __restrict__ act, const float* __restrict__ w2,
        const int* __restrict__ meta, const int* __restrict__ rowTok,
        const float* __restrict__ rowW, float* __restrict__ out) {
    const int ch = blockIdx.x;      // 8 chunks of 256 rows
    const int ht = blockIdx.y;      // 16 tiles of 128 hid cols
    const int e  = blockIdx.z;
    const int r0 = meta[16 + e];
    const int Ne = meta[17 + e] - r0;
    const int cb = ch * 256;
    if (cb >= Ne) return;

    __shared__ __align__(16) char As[3 * 16384];

    GEMM_PRE(act, NINT)

    const int colh = ht * 128 + wc * 32 + cl;
    const float* p0g = w2 + ((size_t)e * HID + colh) * NINT + kq * 8;
    const float* p1g = p0g + (size_t)16 * NINT;

    PIPE(176);  // NINT/32

#pragma unroll
    for (int rf = 0; rf < 4; ++rf) {
#pragma unroll
        for (int j = 0; j < 4; ++j) {
            int r = cb + wr * 64 + rf * 16 + kq * 4 + j;
            if (r < Ne) {
                int slot = r0 + r;
                int tok = rowTok[slot];
                float sw = rowW[slot];
                atomicAdd(&out[(size_t)tok * HID + ht * 128 + wc * 32 + cl],      acc[rf][0][j] * sw);
                atomicAdd(&out[(size_t)tok * HID + ht * 128 + wc * 32 + 16 + cl], acc[rf][1][j] * sw);
            }
        }
    }
}

extern "C" void kernel_launch(void* const* d_in, const int* in_sizes, int n_in,
                              void* d_out, int out_size, void* d_ws, size_t ws_size,
                              hipStream_t stream) {
    const float* x      = (const float*)d_in[0];
    const float* logits = (const float*)d_in[1];
    const float* w1     = (const float*)d_in[2];
    const float* w3     = (const float*)d_in[3];
    const float* w2     = (const float*)d_in[4];
    float* out = (float*)d_out;

    char* ws = (char*)d_ws;
    int*   meta   = (int*)ws;                       // 32 ints
    int*   rowTok = (int*)(ws + 512);               // 4096 ints
    float* rowW   = (float*)(ws + 512 + 16384);     // 4096 floats
    unsigned short* xg  = (unsigned short*)(ws + (1u << 20));   // 16 MB
    unsigned short* act = (unsigned short*)(ws + (18u << 20));  // 44 MB

    zero_kernel<<<4096, 256, 0, stream>>>(out, meta);
    route_count<<<8, 256, 0, stream>>>(logits, meta);
    scan_kernel<<<1, 1, 0, stream>>>(meta);
    route_assign<<<8, 256, 0, stream>>>(logits, meta, rowTok, rowW);
    gather_x<<<4096, 256, 0, stream>>>(x, rowTok, xg);
    gemm1_kernel<<<dim3(8, 88, 8), 1024, 0, stream>>>(xg, w1, w3, meta, act);
    gemm2_kernel<<<dim3(8, 16, 8), 1024, 0, stream>>>(act, w2, meta, rowTok, rowW, out);
}

// Round 9
// 2121.024 us; speedup vs baseline: 2.2550x; 2.2550x over previous
//
#include <hip/hip_runtime.h>
#include <hip/hip_bf16.h>
#include <cstdint>
#include <cstddef>

#define NTOK 2048
#define HID  2048
#define NINT 5632
#define NEXP 8

typedef __attribute__((ext_vector_type(8))) short short8;
typedef __attribute__((ext_vector_type(4))) float f32x4;
typedef __attribute__((ext_vector_type(4))) int   int4v;
typedef __attribute__((ext_vector_type(2))) unsigned int uint2v;
typedef __attribute__((ext_vector_type(4))) float fl4;

__device__ __forceinline__ unsigned short f2bf(float f) {
    union { float f; unsigned int u; } v; v.f = f;
    unsigned int r = (v.u + 0x7fffu + ((v.u >> 16) & 1u)) >> 16;
    return (unsigned short)r;
}

// pack 2 floats -> 2 bf16 (v_cvt_pk_bf16_f32, RNE)
__device__ __forceinline__ unsigned int pk2(float x, float y) {
    __hip_bfloat162 h = __float22bfloat162_rn(make_float2(x, y));
    union { __hip_bfloat162 h; unsigned int u; } c; c.h = h;
    return c.u;
}

// meta layout (ints): [0..7]=cnt, [8..15]=cursor, [16..24]=offs
__global__ void zero_kernel(float* __restrict__ out, int* __restrict__ meta) {
    int idx = blockIdx.x * blockDim.x + threadIdx.x;
    fl4 z = {0.f, 0.f, 0.f, 0.f};
    ((fl4*)out)[idx] = z;
    if (blockIdx.x == 0 && threadIdx.x < 16) meta[threadIdx.x] = 0;
}

__device__ __forceinline__ void top2_route(const float* __restrict__ lg, int t,
                                           int& e0, int& e1, float& w0, float& w1) {
    float l[NEXP];
#pragma unroll
    for (int e = 0; e < NEXP; ++e) l[e] = lg[t * NEXP + e];
    e0 = 0; float b0l = l[0];
#pragma unroll
    for (int e = 1; e < NEXP; ++e) if (l[e] > b0l) { b0l = l[e]; e0 = e; }
    e1 = (e0 == 0) ? 1 : 0; float b1l = l[e1];
#pragma unroll
    for (int e = 0; e < NEXP; ++e) {
        if (e == e0) continue;
        if (l[e] > b1l) { b1l = l[e]; e1 = e; }
    }
    float m = b0l;
    float p0 = __expf(b0l - m), p1 = __expf(b1l - m);
    float inv = 1.f / (p0 + p1);
    w0 = p0 * inv; w1 = p1 * inv;
}

__global__ void route_count(const float* __restrict__ logits, int* __restrict__ meta) {
    int t = blockIdx.x * blockDim.x + threadIdx.x;
    int e0, e1; float w0, w1;
    top2_route(logits, t, e0, e1, w0, w1);
    atomicAdd(&meta[e0], 1);
    atomicAdd(&meta[e1], 1);
}

__global__ void scan_kernel(int* __restrict__ meta) {
    if (threadIdx.x == 0 && blockIdx.x == 0) {
        int s = 0;
#pragma unroll
        for (int e = 0; e < NEXP; ++e) { meta[16 + e] = s; s += meta[e]; }
        meta[16 + NEXP] = s;
    }
}

__global__ void route_assign(const float* __restrict__ logits, int* __restrict__ meta,
                             int* __restrict__ rowTok, float* __restrict__ rowW) {
    int t = blockIdx.x * blockDim.x + threadIdx.x;
    int e0, e1; float w0, w1;
    top2_route(logits, t, e0, e1, w0, w1);
    int p0 = atomicAdd(&meta[8 + e0], 1);
    int s0 = meta[16 + e0] + p0;
    rowTok[s0] = t; rowW[s0] = w0;
    int p1 = atomicAdd(&meta[8 + e1], 1);
    int s1 = meta[16 + e1] + p1;
    rowTok[s1] = t; rowW[s1] = w1;
}

__global__ void gather_x(const float* __restrict__ x, const int* __restrict__ rowTok,
                         unsigned short* __restrict__ xg) {
    int slot = blockIdx.x;
    int tok = rowTok[slot];
    int c = threadIdx.x;
    const fl4* src = (const fl4*)(x + (size_t)tok * HID);
    fl4 a = src[c * 2], b = src[c * 2 + 1];
    short8 v;
    v[0] = (short)f2bf(a[0]); v[1] = (short)f2bf(a[1]); v[2] = (short)f2bf(a[2]); v[3] = (short)f2bf(a[3]);
    v[4] = (short)f2bf(b[0]); v[5] = (short)f2bf(b[1]); v[6] = (short)f2bf(b[2]); v[7] = (short)f2bf(b[3]);
    *(short8*)(xg + (size_t)slot * HID + c * 8) = v;
}

// ======================= GEMM1 =======================
// 256 thr (4 waves). Tile: 128 token-rows x (32 gate + 32 up) cols. BK=64.
// R1 phase order (burst loads -> cvt -> sync -> LDS write -> sync -> MFMA);
// small blocks give 4 blocks/CU so inter-block TLP covers the drain stall.
// LDS: unpadded 128B rows with XOR slot swizzle (verified 0-conflict in R7/R8):
// LDS[row][slot] holds global k-chunk (slot ^ (row&7)).
__global__ __launch_bounds__(256, 4) void gemm1_kernel(
        const unsigned short* __restrict__ xg,
        const float* __restrict__ w1, const float* __restrict__ w3,
        const int* __restrict__ meta, unsigned short* __restrict__ act) {
    const int ch = blockIdx.x;      // 16 chunks of 128 rows (x-fastest: B-panel sharing)
    const int it = blockIdx.y;      // 176 tiles of 32 inter cols
    const int e  = blockIdx.z;      // 8 experts
    const int r0 = meta[16 + e];
    const int Ne = meta[17 + e] - r0;
    const int cb = ch * 128;
    if (cb >= Ne) return;

    __shared__ __align__(16) short As[128][64];   // 16 KB
    __shared__ __align__(16) short Bs[64][64];    // 8 KB (rows 0..31 gate, 32..63 up)

    const int tid = threadIdx.x;
    const int wv = tid >> 6, l = tid & 63;
    const int cl = l & 15, kq = l >> 4;

    // ---- A staging: thread covers 4 rows, 16B slot (tid&7) each ----
    const unsigned short* agp[4];
    short* awr[4];
    {
        const int slot = tid & 7;
#pragma unroll
        for (int j = 0; j < 4; ++j) {
            int row = (tid >> 3) + j * 32;
            int gr = cb + row; if (gr > Ne - 1) gr = Ne - 1;
            agp[j] = xg + (size_t)(r0 + gr) * HID + slot * 8;
            awr[j] = &As[row][(slot ^ (row & 7)) * 8];
        }
    }
    // ---- B staging: 64 rows x 64 k fp32; thread: row tid>>2, 4 chunks ----
    const int brow = tid >> 2, bq = tid & 3;
    const float* bgp = ((brow < 32)
        ? (w1 + ((size_t)e * NINT + (size_t)it * 32 + brow) * HID)
        : (w3 + ((size_t)e * NINT + (size_t)it * 32 + (brow - 32)) * HID)) + bq * 4;
    unsigned int* bwr[4];
#pragma unroll
    for (int j2 = 0; j2 < 4; ++j2) {
        int s = 2 * j2 + (bq >> 1);
        bwr[j2] = (unsigned int*)&Bs[brow][(s ^ (brow & 7)) * 8 + (bq & 1) * 4];
    }

    f32x4 acc[2][4];
#pragma unroll
    for (int rf = 0; rf < 2; ++rf)
#pragma unroll
        for (int cf = 0; cf < 4; ++cf) acc[rf][cf] = (f32x4){0.f, 0.f, 0.f, 0.f};

#pragma unroll 1
    for (int k0 = 0; k0 < HID; k0 += 64) {
        int4v ra[4];
#pragma unroll
        for (int j = 0; j < 4; ++j) ra[j] = *(const int4v*)(agp[j] + k0);
        fl4 rb[4];
#pragma unroll
        for (int j2 = 0; j2 < 4; ++j2) rb[j2] = *(const fl4*)(bgp + k0 + 16 * j2);
        uint2v bw[4];
#pragma unroll
        for (int j2 = 0; j2 < 4; ++j2) {
            bw[j2][0] = pk2(rb[j2][0], rb[j2][1]);
            bw[j2][1] = pk2(rb[j2][2], rb[j2][3]);
        }
        __syncthreads();
#pragma unroll
        for (int j = 0; j < 4; ++j) *(int4v*)awr[j] = ra[j];
#pragma unroll
        for (int j2 = 0; j2 < 4; ++j2) *(uint2v*)bwr[j2] = bw[j2];
        __syncthreads();
#pragma unroll
        for (int kk = 0; kk < 2; ++kk) {
            const int sx = ((kk * 4 + kq) ^ (cl & 7)) * 8;
            short8 af0 = *(const short8*)&As[wv * 32 + cl][sx];
            short8 af1 = *(const short8*)&As[wv * 32 + 16 + cl][sx];
#pragma unroll
            for (int cf = 0; cf < 4; ++cf) {
                short8 bfm = *(const short8*)&Bs[cf * 16 + cl][sx];
                acc[0][cf] = __builtin_amdgcn_mfma_f32_16x16x32_bf16(af0, bfm, acc[0][cf], 0, 0, 0);
                acc[1][cf] = __builtin_amdgcn_mfma_f32_16x16x32_bf16(af1, bfm, acc[1][cf], 0, 0, 0);
            }
        }
    }

    // epilogue: y = silu(gate)*up -> act bf16 (C: col=cl, row=kq*4+j)
#pragma unroll
    for (int rf = 0; rf < 2; ++rf) {
#pragma unroll
        for (int cf = 0; cf < 2; ++cf) {
            f32x4 g = acc[rf][cf], u = acc[rf][cf + 2];
#pragma unroll
            for (int j = 0; j < 4; ++j) {
                int r = cb + wv * 32 + rf * 16 + kq * 4 + j;
                if (r < Ne) {
                    float gv = g[j];
                    float y = gv / (1.f + __expf(-gv)) * u[j];
                    act[(size_t)(r0 + r) * NINT + (size_t)it * 32 + cf * 16 + cl] = f2bf(y);
                }
            }
        }
    }
}

// ======================= GEMM2 =======================
// 256 thr. Tile: 128 rows x 32 hid-cols, K = NINT. Same structure.
__global__ __launch_bounds__(256, 4) void gemm2_kernel(
        const unsigned short* __restrict__ act, const float* __restrict__ w2,
        const int* __restrict__ meta, const int* __restrict__ rowTok,
        const float* __restrict__ rowW, float* __restrict__ out) {
    const int ch = blockIdx.x;      // 16 chunks of 128 rows
    const int ht = blockIdx.y;      // 64 tiles of 32 hid cols
    const int e  = blockIdx.z;
    const int r0 = meta[16 + e];
    const int Ne = meta[17 + e] - r0;
    const int cb = ch * 128;
    if (cb >= Ne) return;

    __shared__ __align__(16) short As[128][64];   // 16 KB
    __shared__ __align__(16) short Bs[32][64];    // 4 KB

    const int tid = threadIdx.x;
    const int wv = tid >> 6, l = tid & 63;
    const int cl = l & 15, kq = l >> 4;

    const unsigned short* agp[4];
    short* awr[4];
    {
        const int slot = tid & 7;
#pragma unroll
        for (int j = 0; j < 4; ++j) {
            int row = (tid >> 3) + j * 32;
            int gr = cb + row; if (gr > Ne - 1) gr = Ne - 1;
            agp[j] = act + (size_t)(r0 + gr) * NINT + slot * 8;
            awr[j] = &As[row][(slot ^ (row & 7)) * 8];
        }
    }
    // B: 32 rows x 64 k fp32; thread: row tid>>3, 2 chunks (coalesced 128B/8 lanes)
    const int brow = tid >> 3, bq = tid & 7;
    const float* bgp = w2 + ((size_t)e * HID + (size_t)ht * 32 + brow) * NINT + bq * 4;
    unsigned int* bwr[2];
#pragma unroll
    for (int j2 = 0; j2 < 2; ++j2) {
        int s = 4 * j2 + (bq >> 1);
        bwr[j2] = (unsigned int*)&Bs[brow][(s ^ (brow & 7)) * 8 + (bq & 1) * 4];
    }

    f32x4 acc[2][2];
#pragma unroll
    for (int rf = 0; rf < 2; ++rf)
#pragma unroll
        for (int cf = 0; cf < 2; ++cf) acc[rf][cf] = (f32x4){0.f, 0.f, 0.f, 0.f};

#pragma unroll 1
    for (int k0 = 0; k0 < NINT; k0 += 64) {
        int4v ra[4];
#pragma unroll
        for (int j = 0; j < 4; ++j) ra[j] = *(const int4v*)(agp[j] + k0);
        fl4 rb[2];
#pragma unroll
        for (int j2 = 0; j2 < 2; ++j2) rb[j2] = *(const fl4*)(bgp + k0 + 32 * j2);
        uint2v bw[2];
#pragma unroll
        for (int j2 = 0; j2 < 2; ++j2) {
            bw[j2][0] = pk2(rb[j2][0], rb[j2][1]);
            bw[j2][1] = pk2(rb[j2][2], rb[j2][3]);
        }
        __syncthreads();
#pragma unroll
        for (int j = 0; j < 4; ++j) *(int4v*)awr[j] = ra[j];
#pragma unroll
        for (int j2 = 0; j2 < 2; ++j2) *(uint2v*)bwr[j2] = bw[j2];
        __syncthreads();
#pragma unroll
        for (int kk = 0; kk < 2; ++kk) {
            const int sx = ((kk * 4 + kq) ^ (cl & 7)) * 8;
            short8 af0 = *(const short8*)&As[wv * 32 + cl][sx];
            short8 af1 = *(const short8*)&As[wv * 32 + 16 + cl][sx];
#pragma unroll
            for (int cf = 0; cf < 2; ++cf) {
                short8 bfm = *(const short8*)&Bs[cf * 16 + cl][sx];
                acc[0][cf] = __builtin_amdgcn_mfma_f32_16x16x32_bf16(af0, bfm, acc[0][cf], 0, 0, 0);
                acc[1][cf] = __builtin_amdgcn_mfma_f32_16x16x32_bf16(af1, bfm, acc[1][cf], 0, 0, 0);
            }
        }
    }

#pragma unroll
    for (int rf = 0; rf < 2; ++rf) {
#pragma unroll
        for (int j = 0; j < 4; ++j) {
            int r = cb + wv * 32 + rf * 16 + kq * 4 + j;
            if (r < Ne) {
                int slot = r0 + r;
                int tok = rowTok[slot];
                float sw = rowW[slot];
#pragma unroll
                for (int cf = 0; cf < 2; ++cf)
                    atomicAdd(&out[(size_t)tok * HID + (size_t)ht * 32 + cf * 16 + cl],
                              acc[rf][cf][j] * sw);
            }
        }
    }
}

extern "C" void kernel_launch(void* const* d_in, const int* in_sizes, int n_in,
                              void* d_out, int out_size, void* d_ws, size_t ws_size,
                              hipStream_t stream) {
    const float* x      = (const float*)d_in[0];
    const float* logits = (const float*)d_in[1];
    const float* w1     = (const float*)d_in[2];
    const float* w3     = (const float*)d_in[3];
    const float* w2     = (const float*)d_in[4];
    float* out = (float*)d_out;

    char* ws = (char*)d_ws;
    int*   meta   = (int*)ws;                       // 32 ints
    int*   rowTok = (int*)(ws + 512);               // 4096 ints
    float* rowW   = (float*)(ws + 512 + 16384);     // 4096 floats
    unsigned short* xg  = (unsigned short*)(ws + (1u << 20));   // 16 MB
    unsigned short* act = (unsigned short*)(ws + (18u << 20));  // 44 MB

    zero_kernel<<<4096, 256, 0, stream>>>(out, meta);
    route_count<<<8, 256, 0, stream>>>(logits, meta);
    scan_kernel<<<1, 1, 0, stream>>>(meta);
    route_assign<<<8, 256, 0, stream>>>(logits, meta, rowTok, rowW);
    gather_x<<<4096, 256, 0, stream>>>(x, rowTok, xg);
    gemm1_kernel<<<dim3(16, 176, 8), 256, 0, stream>>>(xg, w1, w3, meta, act);
    gemm2_kernel<<<dim3(16, 64, 8), 256, 0, stream>>>(act, w2, meta, rowTok, rowW, out);
}